// Round 6
// baseline (851.875 us; speedup 1.0000x reference)
//
#include <hip/hip_runtime.h>

#define VOCAB 12288
#define EMB 128
// R6: tile = 32 ctx-rows (i) x 512 tgt-cols (j). X per tile = 32 rows x 2KB
// CONTIGUOUS per row (vs 128 x 512B before) -> 4x longer DRAM runs.
#define TI 32
#define TJ 512
#define NBI (VOCAB / TI)      // 384
#define NBJ (VOCAB / TJ)      // 24
#define NBLK (NBI * NBJ)      // 9216 (same as before)

typedef unsigned short u16;
typedef __bf16 bf16x8 __attribute__((ext_vector_type(8)));
typedef float f32x4 __attribute__((ext_vector_type(4)));

#define AS1 __attribute__((address_space(1)))
#define AS3 __attribute__((address_space(3)))

__device__ __forceinline__ u16 f2bf(float f) {
    unsigned u = __float_as_uint(f);
    u += 0x7FFF + ((u >> 16) & 1);   // round-to-nearest-even
    return (u16)(u >> 16);
}

__device__ __forceinline__ void load_lds16(const void* g, void* l) {
    __builtin_amdgcn_global_load_lds((AS1 void*)const_cast<void*>(g),
                                     (AS3 void*)l, 16, 0, 0);
}

// hw transcendentals: v_exp_f32 = 2^x, v_log_f32 = log2(x)
__device__ __forceinline__ float hw_exp2(float x) { return __builtin_amdgcn_exp2f(x); }
__device__ __forceinline__ float hw_log2(float x) { return __builtin_amdgcn_logf(x); }

// Kernel 1: zero the output scalar + cast both embedding matrices fp32->bf16 into ws.
__global__ __launch_bounds__(256) void glove_prep(
        const float* __restrict__ tgt, const float* __restrict__ ctx,
        u16* __restrict__ tgtb, u16* __restrict__ ctxb, float* __restrict__ out) {
    int idx = blockIdx.x * 256 + threadIdx.x;
    if (idx == 0) out[0] = 0.0f;
    const int N4 = (VOCAB * EMB) / 4;   // 393216 float4s per matrix
    const float4* __restrict__ s;
    u16* __restrict__ d;
    int k = idx;
    if (k < N4) { s = (const float4*)tgt; d = tgtb; }
    else        { k -= N4; s = (const float4*)ctx; d = ctxb; }
    float4 v = s[k];
    unsigned lo = (unsigned)f2bf(v.x) | ((unsigned)f2bf(v.y) << 16);
    unsigned hi = (unsigned)f2bf(v.z) | ((unsigned)f2bf(v.w) << 16);
    ((uint2*)d)[k] = make_uint2(lo, hi);
}

// Kernel 2: 32x512 output tile per 512-thread block (8 waves, each owning a
// 32x64 j-strip). A (8KB) reg-staged into LDS; B fragments loaded DIRECTLY
// from L2 to registers (tgt bf16 is L2-resident; 128KB B-tile won't fit LDS);
// X tile (64KB) DMA'd into LDS as 32 x 2KB contiguous rows AFTER the MFMA
// phase (vmcnt FIFO: X must not gate the fast B loads); the other resident
// block's compute overlaps the X stream (R5-proven). LDS 72KB -> 2 blk/CU,
// 4 waves/SIMD.
__global__ __launch_bounds__(512, 4) void glove_main(
        const float* __restrict__ X,
        const u16* __restrict__ ctxb, const u16* __restrict__ tgtb,
        const float* __restrict__ tb, const float* __restrict__ cb,
        float* __restrict__ out, float* __restrict__ partial) {
    __shared__ __bf16 smA[TI * EMB];   // 8 KB ctx tile, xor-swizzled 16B chunks
    __shared__ float  smX[TI * TJ];    // 64 KB X tile, bit-swizzled 16B chunks

    const int tid  = threadIdx.x;      // 0..511
    const int lane = tid & 63;
    const int wave = tid >> 6;         // 0..7
    const int quad = lane >> 4;
    const int ln   = lane & 15;

    // XCD swizzle: each XCD owns 3 j-blocks (B working set 384KB -> L2-hot)
    // and sweeps ib sequentially -> its X stream walks rows in order.
    int bid = blockIdx.x;              // 0..9215
    int xcd = bid & 7;
    int idx = bid >> 3;                // 0..1151
    int jb  = xcd * 3 + (idx / NBI);   // 0..23
    int ib  = idx % NBI;               // 0..383

    const int bi = ib * TI;            // ctx row base (i)
    const int bj = jb * TJ;            // tgt row base (j)

    // --- Stage A via regs->LDS, chunk-swizzled: LDS chunk (row,cs) holds
    // global chunk (row, cs ^ (row&15)) -> conflict-free ds_read_b128 frags.
    {
        int row = tid >> 4;            // 0..31
        int c   = tid & 15;
        uint4 v = *(const uint4*)(ctxb + (size_t)(bi + row) * EMB + c * 8);
        int cs  = c ^ (row & 15);
        *(uint4*)(smA + row * EMB + cs * 8) = v;
    }
    __syncthreads();

    // --- MFMA phase. Wave w owns cols [w*64, w*64+64) of the tile.
    const int jw = wave * 64;

    f32x4 acc[2][4];
#pragma unroll
    for (int m = 0; m < 2; ++m)
#pragma unroll
        for (int n = 0; n < 4; ++n)
            acc[m][n] = (f32x4){0.f, 0.f, 0.f, 0.f};

#pragma unroll
    for (int s = 0; s < 4; ++s) {      // K-steps of 32
        bf16x8 af[2], bf[4];
#pragma unroll
        for (int m = 0; m < 2; ++m) {
            int row = m * 16 + ln;                    // row&15 == ln
            int cp  = (s * 4 + quad) ^ ln;            // unswizzle
            af[m] = *(const bf16x8*)(smA + row * EMB + cp * 8);
        }
#pragma unroll
        for (int n = 0; n < 4; ++n) {                 // B direct from L2
            int grow = bj + jw + n * 16 + ln;
            bf[n] = *(const bf16x8*)(tgtb + (size_t)grow * EMB + (s * 4 + quad) * 8);
        }
#pragma unroll
        for (int m = 0; m < 2; ++m)
#pragma unroll
            for (int n = 0; n < 4; ++n)
                acc[m][n] = __builtin_amdgcn_mfma_f32_16x16x32_bf16(
                                af[m], bf[n], acc[m][n], 0, 0, 0);
    }

    // --- X DMA: 64 chunks of 1KB; consecutive instrs of a wave cover one
    // full 2KB row contiguously (rows 4w..4w+3 per wave). Linear LDS dest +
    // pre-swizzled source chunk: chunk bit2 ^= row bit2 (kills the 4-way
    // quad conflict on epilogue reads; swizzle stays inside 128B lines so
    // DRAM sees unbroken 1KB spans).
    const float* gX = X + (size_t)bi * VOCAB + bj;
#pragma unroll
    for (int t = 0; t < 8; ++t) {
        int g    = wave * 8 + t;       // 1-KB chunk id 0..63, wave-uniform
        int row  = g >> 1;             // 0..31
        int half = g & 1;
        int c    = half * 64 + lane;   // 16B chunk within row, 0..127
        int cs   = c ^ (((row >> 2) & 1) << 2);
        load_lds16(gX + (size_t)row * VOCAB + cs * 4, smX + g * 256);
    }
    asm volatile("s_waitcnt vmcnt(0)" ::: "memory");   // only X outstanding here
    __builtin_amdgcn_s_barrier();

    // --- Epilogue. C/D: col j = n*16 + ln, row i = m*16 + quad*4 + r.
    float tbv[4];
#pragma unroll
    for (int n = 0; n < 4; ++n) tbv[n] = tb[bj + jw + n * 16 + ln];

    const float LN2 = 0.69314718055994531f;
    float sum = 0.0f;
#pragma unroll
    for (int m = 0; m < 2; ++m) {
#pragma unroll
        for (int r = 0; r < 4; ++r) {
            int il = m * 16 + quad * 4 + r;            // tile-local X row
            float cbi = cb[bi + il];
            const float* xrow = smX + il * TJ;
            int swz = ((il >> 2) & 1) << 2;
#pragma unroll
            for (int n = 0; n < 4; ++n) {
                int jl = jw + n * 16 + ln;             // tile-local X col
                int cr = (jl >> 2) ^ swz;              // unswizzle 16B chunk
                float x  = xrow[(cr << 2) + (jl & 3)];
                float d  = acc[m][n][r] + tbv[n] + cbi - LN2 * hw_log2(1.0f + x);
                float xs = x * 0.01f;
                float w  = hw_exp2(0.75f * hw_log2(xs));   // xs^0.75; xs=0 -> 0
                w = fminf(w, 1.0f);
                sum = fmaf(w * d, d, sum);
            }
        }
    }

    // wave reduce -> cross-wave via LDS (smA dead: all waves passed the X
    // barrier, which is after every smA read) -> one plain store per block.
#pragma unroll
    for (int off = 32; off > 0; off >>= 1) sum += __shfl_down(sum, off);

    float* red = (float*)smA;
    if (lane == 0) red[wave] = sum;
    __syncthreads();
    if (tid == 0) {
        float v = 0.f;
#pragma unroll
        for (int w2 = 0; w2 < 8; ++w2) v += red[w2];
        if (partial) partial[blockIdx.x] = v;   // no same-line contention
        else         atomicAdd(out, v);         // fallback if ws too small
    }
}

// Kernel 3: reduce the 9216 per-block partials (36KB, L2-hot) into out[0].
__global__ __launch_bounds__(256) void glove_reduce(
        const float* __restrict__ partial, float* __restrict__ out) {
    int tid = threadIdx.x;
    float s = 0.0f;
    const float4* p4 = (const float4*)partial;
    for (int k = tid; k < NBLK / 4; k += 256) {
        float4 v = p4[k];
        s += v.x + v.y + v.z + v.w;
    }
#pragma unroll
    for (int off = 32; off > 0; off >>= 1) s += __shfl_down(s, off);
    __shared__ float red[4];
    if ((tid & 63) == 0) red[tid >> 6] = s;
    __syncthreads();
    if (tid == 0) out[0] = red[0] + red[1] + red[2] + red[3];
}

extern "C" void kernel_launch(void* const* d_in, const int* in_sizes, int n_in,
                              void* d_out, int out_size, void* d_ws, size_t ws_size,
                              hipStream_t stream) {
    const float* X   = (const float*)d_in[0];
    const float* tgt = (const float*)d_in[1];
    const float* ctx = (const float*)d_in[2];
    const float* tb  = (const float*)d_in[3];
    const float* cb  = (const float*)d_in[4];
    float* out = (float*)d_out;

    u16* tgtb = (u16*)d_ws;
    u16* ctxb = tgtb + (size_t)VOCAB * EMB;

    // partial-sum array right after the two bf16 matrices (offset 6291456 B, 16B-aligned)
    const size_t emb_bytes = (size_t)VOCAB * EMB * sizeof(u16) * 2;
    float* partial = nullptr;
    if (ws_size >= emb_bytes + (size_t)NBLK * sizeof(float))
        partial = (float*)((char*)d_ws + emb_bytes);

    glove_prep<<<dim3(2 * (VOCAB * EMB / 4) / 256), 256, 0, stream>>>(
        tgt, ctx, tgtb, ctxb, out);
    glove_main<<<dim3(NBLK), 512, 0, stream>>>(
        X, ctxb, tgtb, tb, cb, out, partial);
    if (partial)
        glove_reduce<<<dim3(1), 256, 0, stream>>>(partial, out);
}